// Round 4
// baseline (1032199.805 us; speedup 1.0000x reference)
//
#include <hip/hip_runtime.h>
#include <math.h>

typedef unsigned short u16;
typedef __attribute__((ext_vector_type(8))) short short8;
typedef __attribute__((ext_vector_type(4))) float f32x4;

__device__ __forceinline__ float sigm(float x) { return 1.0f / (1.0f + expf(-x)); }

__device__ __forceinline__ u16 f2bf(float x) {
    union { float f; unsigned u; } v; v.f = x;
    unsigned r = v.u + 0x7fffu + ((v.u >> 16) & 1u);
    return (u16)(r >> 16);
}
__device__ __forceinline__ float bf2f(u16 h) {
    union { unsigned u; float f; } v; v.u = ((unsigned)h) << 16;
    return v.f;
}
__device__ __forceinline__ f32x4 mfma16(short8 a, short8 b, f32x4 c) {
    return __builtin_amdgcn_mfma_f32_16x16x32_bf16(a, b, c, 0, 0, 0);
}
__device__ __forceinline__ void gl_lds16(const void* g, void* l) {
    __builtin_amdgcn_global_load_lds(
        (const __attribute__((address_space(1))) unsigned int*)g,
        (__attribute__((address_space(3))) unsigned int*)l, 16, 0, 0);
}
__device__ __forceinline__ int swz(int c) { return (c ^ (c >> 2)) & 3; }

// ---------------------------------------------------------------------------
// k_step: ONE kernel per timestep (no atomics).
//   z[m, col'] = A[m, koff..] @ W[col', koff..]^T + BR[col']   (3-product bf16)
//   col' = dir*4096 + u*4 + g. A = [hf | hb] (stride 2048) bf16 hi/lo.
//   Gates -> c (fp32 in place), h -> bf16 hi/lo into next-A planes.
//   fc1 for time t-1: designated fwd blocks (bid==0,128) accumulate
//   relu(hi+lo).Wfc1 from their A fragments in-loop, plain-store out[m,t-1].
// Grid 256 blocks: bid = rowhalf*128 + g2; g2<64: fwd col-group, else bwd.
// Block tile 64 rows x 64 cols; 4 waves of 32x32. K-chunk 64, LDS dbuf.
// ---------------------------------------------------------------------------
__global__ __launch_bounds__(256, 1) void k_step(
    const u16* __restrict__ Ah, const u16* __restrict__ Al,
    u16* __restrict__ NAh, u16* __restrict__ NAl,
    const u16* __restrict__ WH, const u16* __restrict__ WL, int wstride,
    int koff_f, int nch_f, int koff_b, int nch_b,
    const float* __restrict__ BR, float* __restrict__ CF, float* __restrict__ CB,
    const float* __restrict__ Wfc1, const float* __restrict__ bfc1,
    float* __restrict__ out, int T, int t)
{
    __shared__ __align__(16) char sm[32768];   // 2 x 16KB W bufs; epi reuses [0,18432)

    const int tid = threadIdx.x, bid = blockIdx.x;
    const int w = tid >> 6, lane = tid & 63, l15 = lane & 15, quad = lane >> 4;
    const int g2 = bid & 127, rowhalf = bid >> 7;
    const int dir = g2 >= 64;
    const int colgrp = dir ? (g2 - 64) : g2;
    const int nbase = dir * 4096 + colgrp * 64;
    const int koff = dir ? koff_b : koff_f;
    const int nch  = dir ? nch_b : nch_f;
    const int wr = w & 1, wc = w >> 1;
    const int r0 = rowhalf * 64 + wr * 32;   // first of 32 rows for this wave
    const int c0 = wc * 32;                  // first of 32 block-local cols

    // fc1 duty: only fwd colgrp-0 blocks, wc==0 waves, and only when t>0
    const bool fc1w = (t > 0) && (g2 == 0) && (wc == 0);

    // --- staging role: plane sp (0 hi, 1 lo), k-half skh ---
    const int sp = w >> 1, skh = w & 1;
    const u16* Wsrc = sp ? WL : WH;
    size_t soff[4];
    int sldsoff[4];
#pragma unroll
    for (int i = 0; i < 4; ++i) {
        const int col = i * 16 + (lane >> 2);
        const int s = (lane & 3) ^ swz(col);
        soff[i] = (size_t)(nbase + col) * wstride + (size_t)(koff + skh * 32 + s * 8);
        sldsoff[i] = sp * 8192 + skh * 4096 + i * 1024;
    }

    // --- A fragment base offsets ---
    size_t aoff[2];   // per m-tile
#pragma unroll
    for (int mt = 0; mt < 2; ++mt)
        aoff[mt] = (size_t)(r0 + mt * 16 + l15) * 2048 + (size_t)(koff + quad * 8);

    f32x4 acc[2][2] = {};
    short8 ah[2][2][2], al_[2][2][2];   // [buf][mt][ksl]
    float fs0 = 0.0f, fs1 = 0.0f;       // fc1 partials per m-tile

    // prologue: stage chunk 0, load A chunk 0
#pragma unroll
    for (int i = 0; i < 4; ++i) gl_lds16(Wsrc + soff[i], sm + sldsoff[i]);
#pragma unroll
    for (int mt = 0; mt < 2; ++mt)
#pragma unroll
        for (int ksl = 0; ksl < 2; ++ksl) {
            ah[0][mt][ksl]  = *(const short8*)(Ah + aoff[mt] + ksl * 32);
            al_[0][mt][ksl] = *(const short8*)(Al + aoff[mt] + ksl * 32);
        }

    for (int c = 0; c < nch; ++c) {
        __syncthreads();
        const int cur = c & 1, nxt = cur ^ 1;
        if (c + 1 < nch) {
            const int k1 = (c + 1) * 64;
#pragma unroll
            for (int i = 0; i < 4; ++i)
                gl_lds16(Wsrc + soff[i] + k1, sm + nxt * 16384 + sldsoff[i]);
#pragma unroll
            for (int mt = 0; mt < 2; ++mt)
#pragma unroll
                for (int ksl = 0; ksl < 2; ++ksl) {
                    ah[nxt][mt][ksl]  = *(const short8*)(Ah + aoff[mt] + k1 + ksl * 32);
                    al_[nxt][mt][ksl] = *(const short8*)(Al + aoff[mt] + k1 + ksl * 32);
                }
        }
        const char* bb = sm + cur * 16384;
#pragma unroll
        for (int ksl = 0; ksl < 2; ++ksl) {
            short8 bh[2], bl[2];
#pragma unroll
            for (int nt = 0; nt < 2; ++nt) {
                const int col = c0 + nt * 16 + l15;
                const int off = ksl * 4096 + col * 64 + ((quad ^ swz(col)) * 16);
                bh[nt] = *(const short8*)(bb + off);
                bl[nt] = *(const short8*)(bb + 8192 + off);
            }
#pragma unroll
            for (int mt = 0; mt < 2; ++mt)
#pragma unroll
                for (int nt = 0; nt < 2; ++nt) {
                    acc[mt][nt] = mfma16(ah[cur][mt][ksl], bh[nt], acc[mt][nt]);
                    acc[mt][nt] = mfma16(al_[cur][mt][ksl], bh[nt], acc[mt][nt]);
                    acc[mt][nt] = mfma16(ah[cur][mt][ksl], bl[nt], acc[mt][nt]);
                }
        }
        // fc1 accumulation from already-loaded A fragments (2 blocks, 2 waves)
        if (fc1w) {
            const int kb = c * 64 + quad * 8;
#pragma unroll
            for (int ksl = 0; ksl < 2; ++ksl) {
                const float* wp = Wfc1 + kb + ksl * 32;
                const f32x4 w0 = *(const f32x4*)(wp);
                const f32x4 w1 = *(const f32x4*)(wp + 4);
#pragma unroll
                for (int mt = 0; mt < 2; ++mt) {
                    const short8 hv = ah[cur][mt][ksl];
                    const short8 lv = al_[cur][mt][ksl];
                    float* fs = mt ? &fs1 : &fs0;
#pragma unroll
                    for (int e = 0; e < 8; ++e) {
                        const float v = bf2f((u16)hv[e]) + bf2f((u16)lv[e]);
                        const float wv = (e < 4) ? w0[e] : w1[e - 4];
                        *fs = fmaf(fmaxf(v, 0.0f), wv, *fs);
                    }
                }
            }
        }
    }

    __syncthreads();

    // fc1 reduce + store (no LDS, no atomics)
    if (fc1w) {
#pragma unroll
        for (int mt = 0; mt < 2; ++mt) {
            float v = mt ? fs1 : fs0;
            v += __shfl_xor(v, 16);
            v += __shfl_xor(v, 32);
            if (lane < 16) {
                const int m = r0 + mt * 16 + l15;
                out[(size_t)m * T + (t - 1)] = v + bfc1[0];
            }
        }
    }

    // z tile -> LDS transpose (per-wave 32x32, stride 36 floats = 144 B)
    char* zb = sm + w * 4608;
#pragma unroll
    for (int mt = 0; mt < 2; ++mt)
#pragma unroll
        for (int nt = 0; nt < 2; ++nt)
#pragma unroll
            for (int r = 0; r < 4; ++r)
                *(float*)(zb + (mt * 16 + quad * 4 + r) * 144 + (nt * 16 + l15) * 4)
                    = acc[mt][nt][r];
    __syncthreads();

    float* C = dir ? CB : CF;
#pragma unroll
    for (int p4 = 0; p4 < 4; ++p4) {
        const int idx = p4 * 64 + lane;
        const int ml = idx >> 3;      // 0..31
        const int ul = idx & 7;       // 0..7
        const f32x4 z = *(const f32x4*)(zb + ml * 144 + ul * 16);
        const f32x4 b4 = *(const f32x4*)(BR + nbase + c0 + ul * 4);
        const float zi = z[0] + b4[0], zf = z[1] + b4[1];
        const float zg = z[2] + b4[2], zo = z[3] + b4[3];
        const int u = colgrp * 16 + wc * 8 + ul;     // unit within direction
        const int m = r0 + ml;
        const size_t cidx = (size_t)m * 1024 + u;
        const float cold = C[cidx];
        const float c2 = sigm(zf) * cold + sigm(zi) * tanhf(zg);
        const float h2 = sigm(zo) * tanhf(c2);
        C[cidx] = c2;
        const size_t hidx = (size_t)m * 2048 + dir * 1024 + u;
        const u16 hh = f2bf(h2);
        NAh[hidx] = hh;
        NAl[hidx] = f2bf(h2 - bf2f(hh));
    }
}

// ---------------------------------------------------------------------------
// k_tail: out[:, T-1] from final A planes. 128 blocks (one per row).
// ---------------------------------------------------------------------------
__global__ __launch_bounds__(256) void k_tail(
    const u16* __restrict__ Ah, const u16* __restrict__ Al,
    const float* __restrict__ Wfc1, const float* __restrict__ bfc1,
    float* __restrict__ out, int T)
{
    __shared__ float red[256];
    const int m = blockIdx.x, tid = threadIdx.x;
    const size_t base = (size_t)m * 2048 + tid * 8;
    const short8 hv = *(const short8*)(Ah + base);
    const short8 lv = *(const short8*)(Al + base);
    float s = 0.0f;
#pragma unroll
    for (int e = 0; e < 8; ++e) {
        const float v = bf2f((u16)hv[e]) + bf2f((u16)lv[e]);
        s = fmaf(fmaxf(v, 0.0f), Wfc1[tid * 8 + e], s);
    }
    red[tid] = s;
    __syncthreads();
    for (int off = 128; off > 0; off >>= 1) {
        if (tid < off) red[tid] += red[tid + off];
        __syncthreads();
    }
    if (tid == 0) out[(size_t)m * T + T - 1] = red[0] + bfc1[0];
}

// ---------------------------------------------------------------------------
// k_fold: W'[col'][1024+j] = (Wih' @ WoT^T)[col'][j]  (+ Whh_b for bwd cols)
// ---------------------------------------------------------------------------
__global__ __launch_bounds__(256, 1) void k_fold(
    const u16* __restrict__ AH, const u16* __restrict__ AL,   // Wih' 8192x512
    const u16* __restrict__ BH, const u16* __restrict__ BL,   // WoT 1024x512
    const float* __restrict__ Whh_b,
    u16* __restrict__ WH, u16* __restrict__ WL)
{
    const int tid = threadIdx.x, bid = blockIdx.x;
    const int w = tid >> 6, lane = tid & 63, l15 = lane & 15, quad = lane >> 4;
    const int bm = bid >> 4, bn = bid & 15;
    const int ar0 = bm * 64 + (w & 1) * 32;
    const int br0 = bn * 64 + (w >> 1) * 32;
    f32x4 acc[2][2] = {};
    for (int k0 = 0; k0 < 512; k0 += 32) {
        short8 a_h[2], a_l[2], b_h[2], b_l[2];
#pragma unroll
        for (int mt = 0; mt < 2; ++mt) {
            const size_t o = (size_t)(ar0 + mt * 16 + l15) * 512 + k0 + quad * 8;
            a_h[mt] = *(const short8*)(AH + o);
            a_l[mt] = *(const short8*)(AL + o);
        }
#pragma unroll
        for (int nt = 0; nt < 2; ++nt) {
            const size_t o = (size_t)(br0 + nt * 16 + l15) * 512 + k0 + quad * 8;
            b_h[nt] = *(const short8*)(BH + o);
            b_l[nt] = *(const short8*)(BL + o);
        }
#pragma unroll
        for (int mt = 0; mt < 2; ++mt)
#pragma unroll
            for (int nt = 0; nt < 2; ++nt) {
                acc[mt][nt] = mfma16(a_h[mt], b_h[nt], acc[mt][nt]);
                acc[mt][nt] = mfma16(a_l[mt], b_h[nt], acc[mt][nt]);
                acc[mt][nt] = mfma16(a_h[mt], b_l[nt], acc[mt][nt]);
            }
    }
#pragma unroll
    for (int mt = 0; mt < 2; ++mt)
#pragma unroll
        for (int nt = 0; nt < 2; ++nt)
#pragma unroll
            for (int r = 0; r < 4; ++r) {
                const int row = ar0 + mt * 16 + quad * 4 + r;   // col'
                const int j = br0 + nt * 16 + l15;
                float v = acc[mt][nt][r];
                if (row >= 4096)
                    v += Whh_b[(size_t)((row & 3) * 1024 + ((row & 4095) >> 2)) * 1024 + j];
                const size_t d = (size_t)row * 2048 + 1024 + j;
                const u16 hh = f2bf(v);
                WH[d] = hh;
                WL[d] = f2bf(v - bf2f(hh));
            }
}

// ---------------------------------------------------------------------------
// k_prep: Wih' hi/lo, WoT hi/lo, BR0/BR1, A0 (x=dec), out=b_fc1, Whh_f -> W'.
// ---------------------------------------------------------------------------
__global__ __launch_bounds__(256) void k_prep(
    const float* __restrict__ dec,
    const float* __restrict__ Wih_f, const float* __restrict__ Whh_f,
    const float* __restrict__ b_f, const float* __restrict__ Wih_b,
    const float* __restrict__ b_b, const float* __restrict__ W_out,
    const float* __restrict__ b_out, const float* __restrict__ b_fc1,
    u16* __restrict__ WihH, u16* __restrict__ WihL,
    u16* __restrict__ WoTH, u16* __restrict__ WoTL,
    float* __restrict__ BR0, float* __restrict__ BR1,
    u16* __restrict__ A0h, u16* __restrict__ A0l,
    u16* __restrict__ WH, u16* __restrict__ WL,
    float* __restrict__ out, int out_size)
{
    const int t = blockIdx.x * 256 + threadIdx.x;
    if (t < 524288) {                       // Wih' (gate-interleaved cols, K=512)
        const int colp = t >> 6, kb = (t & 63) * 8;
        const int dir = colp >> 12, u = (colp & 4095) >> 2, g = colp & 3;
        const float* src = (dir ? Wih_b : Wih_f) + (size_t)(g * 1024 + u) * 512 + kb;
        const size_t d = (size_t)colp * 512 + kb;
#pragma unroll
        for (int j = 0; j < 8; ++j) {
            const float v = src[j];
            const u16 hh = f2bf(v);
            WihH[d + j] = hh; WihL[d + j] = f2bf(v - bf2f(hh));
        }
    } else if (t < 589824) {                // WoT[j][l] = W_out[l][j]
        const int i = t - 524288, jc = i >> 6, lb = (i & 63) * 8;
#pragma unroll
        for (int jj = 0; jj < 8; ++jj) {
            const float v = W_out[(size_t)(lb + jj) * 1024 + jc];
            const size_t d = (size_t)jc * 512 + lb + jj;
            const u16 hh = f2bf(v);
            WoTH[d] = hh; WoTL[d] = f2bf(v - bf2f(hh));
        }
    } else if (t < 598016) {                // biases
        const int colp = t - 589824;
        const int dir = colp >> 12, u = (colp & 4095) >> 2, g = colp & 3;
        const float* Wih = dir ? Wih_b : Wih_f;
        const float s = (dir ? b_b : b_f)[g * 1024 + u];
        BR0[colp] = s;
        float dot = 0.0f;
        for (int l = 0; l < 512; ++l)
            dot += Wih[(size_t)(g * 1024 + u) * 512 + l] * b_out[l];
        BR1[colp] = s + dot;
    } else if (t < 606208) {                // A0 = dec (cols [0,512), stride 2048)
        const int i = t - 598016, m = i >> 6, kb = (i & 63) * 8;
#pragma unroll
        for (int j = 0; j < 8; ++j) {
            const float v = dec[(size_t)m * 512 + kb + j];
            const size_t d = (size_t)m * 2048 + kb + j;
            const u16 hh = f2bf(v);
            A0h[d] = hh; A0l[d] = f2bf(v - bf2f(hh));
        }
    } else if (t < 614400) {                // out init = b_fc1 (safety net)
        const int base = (t - 606208) * 8;
        const float b0 = b_fc1[0];
#pragma unroll
        for (int j = 0; j < 8; ++j)
            if (base + j < out_size) out[base + j] = b0;
    } else {                                // Whh_f -> W' fwd cols, k in [0,1024)
        const int i = t - 614400, colp = i >> 7, kb = (i & 127) * 8;
        const int u = colp >> 2, g = colp & 3;
        const float* src = Whh_f + (size_t)(g * 1024 + u) * 1024 + kb;
        const size_t d = (size_t)colp * 2048 + kb;
#pragma unroll
        for (int j = 0; j < 8; ++j) {
            const float v = src[j];
            const u16 hh = f2bf(v);
            WH[d + j] = hh; WL[d + j] = f2bf(v - bf2f(hh));
        }
    }
}

// ---------------------------------------------------------------------------
// ws layout: see R3 (unchanged).
// ---------------------------------------------------------------------------
extern "C" void kernel_launch(void* const* d_in, const int* in_sizes, int n_in,
                              void* d_out, int out_size, void* d_ws, size_t ws_size,
                              hipStream_t stream) {
    const float* dec   = (const float*)d_in[0];
    const float* Wih_f = (const float*)d_in[2];
    const float* Whh_f = (const float*)d_in[3];
    const float* b_f   = (const float*)d_in[4];
    const float* Wih_b = (const float*)d_in[5];
    const float* Whh_b = (const float*)d_in[6];
    const float* b_b   = (const float*)d_in[7];
    const float* W_out = (const float*)d_in[8];
    const float* b_out = (const float*)d_in[9];
    const float* W_fc1 = (const float*)d_in[10];
    const float* b_fc1 = (const float*)d_in[11];
    float* out = (float*)d_out;

    char* ws = (char*)d_ws;
    u16* WH    = (u16*)(ws);
    u16* WL    = (u16*)(ws + 33554432);
    u16* WihH  = (u16*)(ws + 67108864);
    u16* WihL  = (u16*)(ws + 75497472);
    u16* WoTH  = (u16*)(ws + 83886080);
    u16* WoTL  = (u16*)(ws + 84934656);
    u16* A0h   = (u16*)(ws + 85983232);
    u16* A0l   = (u16*)(ws + 86507520);
    u16* A1h   = (u16*)(ws + 87031808);
    u16* A1l   = (u16*)(ws + 87556096);
    float* CF  = (float*)(ws + 88080384);
    float* CB  = (float*)(ws + 88604672);
    float* BR0 = (float*)(ws + 89128960);
    float* BR1 = (float*)(ws + 89161728);

    k_prep<<<4448, 256, 0, stream>>>(dec, Wih_f, Whh_f, b_f, Wih_b, b_b,
                                     W_out, b_out, b_fc1,
                                     WihH, WihL, WoTH, WoTL, BR0, BR1,
                                     A0h, A0l, WH, WL, out, out_size);
    k_fold<<<2048, 256, 0, stream>>>(WihH, WihL, WoTH, WoTL, Whh_b, WH, WL);
    hipMemsetAsync(CF, 0, 1048576, stream);   // CF + CB contiguous

    const int T = out_size / 128;
    u16* Abh[2] = {A0h, A1h};
    u16* Abl[2] = {A0l, A1l};
    for (int t = 0; t < T; ++t) {
        const int in = t & 1, nx = in ^ 1;
        if (t == 0) {
            k_step<<<256, 256, 0, stream>>>(A0h, A0l, A1h, A1l,
                                            WihH, WihL, 512, 0, 8, 0, 8,
                                            BR0, CF, CB, W_fc1, b_fc1, out, T, 0);
        } else {
            k_step<<<256, 256, 0, stream>>>(Abh[in], Abl[in], Abh[nx], Abl[nx],
                                            WH, WL, 2048, 0, 32, 1024, 16,
                                            BR1, CF, CB, W_fc1, b_fc1, out, T, t);
        }
    }
    k_tail<<<128, 256, 0, stream>>>(Abh[T & 1], Abl[T & 1], W_fc1, b_fc1, out, T);
}

// Round 5
// 26976.352 us; speedup vs baseline: 38.2631x; 38.2631x over previous
//
#include <hip/hip_runtime.h>
#include <math.h>

typedef unsigned short u16;
typedef __attribute__((ext_vector_type(8))) short short8;
typedef __attribute__((ext_vector_type(4))) float f32x4;

__device__ __forceinline__ float sigm(float x) { return 1.0f / (1.0f + expf(-x)); }

__device__ __forceinline__ u16 f2bf(float x) {
    union { float f; unsigned u; } v; v.f = x;
    unsigned r = v.u + 0x7fffu + ((v.u >> 16) & 1u);
    return (u16)(r >> 16);
}
__device__ __forceinline__ float bf2f(u16 h) {
    union { unsigned u; float f; } v; v.u = ((unsigned)h) << 16;
    return v.f;
}
__device__ __forceinline__ f32x4 mfma16(short8 a, short8 b, f32x4 c) {
    return __builtin_amdgcn_mfma_f32_16x16x32_bf16(a, b, c, 0, 0, 0);
}
__device__ __forceinline__ void gl_lds16(const void* g, void* l) {
    __builtin_amdgcn_global_load_lds(
        (const __attribute__((address_space(1))) unsigned int*)g,
        (__attribute__((address_space(3))) unsigned int*)l, 16, 0, 0);
}
__device__ __forceinline__ int swz(int c) { return (c ^ (c >> 2)) & 3; }

// ---------------------------------------------------------------------------
// k_step: ONE kernel per timestep (no atomics, no dynamic reg indexing).
//   z[m, col'] = A[m, koff..] @ W[col', koff..]^T + BR[col']   (3-product bf16)
//   col' = dir*4096 + u*4 + g. A = [hf | hb] (stride 2048) bf16 hi/lo.
//   Gates -> c (fp32 in place), h -> bf16 hi/lo into next-A planes.
//   fc1(t-1): fwd g2==0 blocks, wc==0 waves accumulate relu(hi+lo).Wfc1 from
//   their already-loaded A fragments; butterfly-reduce; plain store out[m,t-1].
// Grid 256 blocks: bid = rowhalf*128 + g2; g2<64: fwd col-group, else bwd.
// Block tile 64 rows x 64 cols; 4 waves of 32x32. K-chunk 64, LDS dbuf.
// K-loop steps by 2 chunks; register double-buffers are separate named arrays
// (static indices only) so nothing spills to scratch.
// ---------------------------------------------------------------------------
#define STAGE_W(kk, buf)                                                      \
    do {                                                                      \
        _Pragma("unroll") for (int i_ = 0; i_ < 4; ++i_)                      \
            gl_lds16(Wsrc + soff[i_] + (kk),                                  \
                     sm + (buf) * 16384 + sldsoff[i_]);                       \
    } while (0)

#define LOAD_A(kk, AH_, AL_)                                                  \
    do {                                                                      \
        _Pragma("unroll") for (int mt_ = 0; mt_ < 2; ++mt_)                   \
            _Pragma("unroll") for (int ks_ = 0; ks_ < 2; ++ks_) {             \
                AH_[mt_][ks_] = *(const short8*)(Ah + aoff[mt_] + (kk) + ks_ * 32); \
                AL_[mt_][ks_] = *(const short8*)(Al + aoff[mt_] + (kk) + ks_ * 32); \
            }                                                                 \
    } while (0)

#define COMPUTE(buf, AH_, AL_, cix)                                           \
    do {                                                                      \
        const char* bb_ = sm + (buf) * 16384;                                 \
        _Pragma("unroll") for (int ks_ = 0; ks_ < 2; ++ks_) {                 \
            short8 bh_[2], bl_[2];                                            \
            _Pragma("unroll") for (int nt_ = 0; nt_ < 2; ++nt_) {             \
                const int col_ = c0 + nt_ * 16 + l15;                         \
                const int off_ = ks_ * 4096 + col_ * 64 + ((quad ^ swz(col_)) * 16); \
                bh_[nt_] = *(const short8*)(bb_ + off_);                      \
                bl_[nt_] = *(const short8*)(bb_ + 8192 + off_);               \
            }                                                                 \
            _Pragma("unroll") for (int mt_ = 0; mt_ < 2; ++mt_)               \
                _Pragma("unroll") for (int nt_ = 0; nt_ < 2; ++nt_) {         \
                    acc[mt_][nt_] = mfma16(AH_[mt_][ks_], bh_[nt_], acc[mt_][nt_]); \
                    acc[mt_][nt_] = mfma16(AL_[mt_][ks_], bh_[nt_], acc[mt_][nt_]); \
                    acc[mt_][nt_] = mfma16(AH_[mt_][ks_], bl_[nt_], acc[mt_][nt_]); \
                }                                                             \
        }                                                                     \
        if (fc1w) {                                                           \
            const int kb_ = (cix) * 64 + quad * 8;                            \
            _Pragma("unroll") for (int ks_ = 0; ks_ < 2; ++ks_) {             \
                const float* wp_ = Wfc1 + kb_ + ks_ * 32;                     \
                const f32x4 w0_ = *(const f32x4*)(wp_);                       \
                const f32x4 w1_ = *(const f32x4*)(wp_ + 4);                   \
                _Pragma("unroll") for (int mt_ = 0; mt_ < 2; ++mt_) {         \
                    const short8 hv_ = AH_[mt_][ks_];                         \
                    const short8 lv_ = AL_[mt_][ks_];                         \
                    _Pragma("unroll") for (int e_ = 0; e_ < 8; ++e_) {        \
                        const float v_ = bf2f((u16)hv_[e_]) + bf2f((u16)lv_[e_]); \
                        const float wv_ = (e_ < 4) ? w0_[e_] : w1_[e_ - 4];   \
                        fsum[mt_] = fmaf(fmaxf(v_, 0.0f), wv_, fsum[mt_]);    \
                    }                                                         \
                }                                                             \
            }                                                                 \
        }                                                                     \
    } while (0)

__global__ __launch_bounds__(256, 1) void k_step(
    const u16* __restrict__ Ah, const u16* __restrict__ Al,
    u16* __restrict__ NAh, u16* __restrict__ NAl,
    const u16* __restrict__ WH, const u16* __restrict__ WL, int wstride,
    int koff_f, int nch_f, int koff_b, int nch_b,
    const float* __restrict__ BR, float* __restrict__ CF, float* __restrict__ CB,
    const float* __restrict__ Wfc1, const float* __restrict__ bfc1,
    float* __restrict__ out, int T, int t)
{
    __shared__ __align__(16) char sm[32768];   // 2 x 16KB W bufs; epi reuses [0,18432)

    const int tid = threadIdx.x, bid = blockIdx.x;
    const int w = tid >> 6, lane = tid & 63, l15 = lane & 15, quad = lane >> 4;
    const int g2 = bid & 127, rowhalf = bid >> 7;
    const int dir = g2 >= 64;
    const int colgrp = dir ? (g2 - 64) : g2;
    const int nbase = dir * 4096 + colgrp * 64;
    const int koff = dir ? koff_b : koff_f;
    const int nch  = dir ? nch_b : nch_f;
    const int wr = w & 1, wc = w >> 1;
    const int r0 = rowhalf * 64 + wr * 32;   // first of 32 rows for this wave
    const int c0 = wc * 32;                  // first of 32 block-local cols

    // fc1 duty: only fwd colgrp-0 blocks, wc==0 waves, and only when t>0
    const bool fc1w = (t > 0) && (g2 == 0) && (wc == 0);

    // --- staging role: plane sp (0 hi, 1 lo), k-half skh ---
    const int sp = w >> 1, skh = w & 1;
    const u16* Wsrc = sp ? WL : WH;
    size_t soff[4];
    int sldsoff[4];
#pragma unroll
    for (int i = 0; i < 4; ++i) {
        const int col = i * 16 + (lane >> 2);
        const int s = (lane & 3) ^ swz(col);
        soff[i] = (size_t)(nbase + col) * wstride + (size_t)(koff + skh * 32 + s * 8);
        sldsoff[i] = sp * 8192 + skh * 4096 + i * 1024;
    }

    // --- A fragment base offsets ---
    size_t aoff[2];
#pragma unroll
    for (int mt = 0; mt < 2; ++mt)
        aoff[mt] = (size_t)(r0 + mt * 16 + l15) * 2048 + (size_t)(koff + quad * 8);

    f32x4 acc[2][2] = {};
    short8 ahA[2][2], alA[2][2], ahB[2][2], alB[2][2];   // static-indexed only
    float fsum[2] = {0.0f, 0.0f};

    // prologue: stage chunk 0 -> LDS buf0, load A chunk 0 -> set A
    STAGE_W(0, 0);
    LOAD_A(0, ahA, alA);

    for (int c = 0; c < nch; c += 2) {
        __syncthreads();                     // buf0 staged (prologue / prev iter)
        {
            const int k1 = (c + 1) * 64;     // c+1 < nch always (nch even)
            STAGE_W(k1, 1);
            LOAD_A(k1, ahB, alB);
        }
        COMPUTE(0, ahA, alA, c);
        __syncthreads();                     // buf1 staged; buf0 free
        if (c + 2 < nch) {
            const int k2 = (c + 2) * 64;
            STAGE_W(k2, 0);
            LOAD_A(k2, ahA, alA);
        }
        COMPUTE(1, ahB, alB, c + 1);
    }

    __syncthreads();    // everyone done with staging bufs before epi overwrite

    // fc1 reduce + store (no LDS, no atomics)
    if (fc1w) {
#pragma unroll
        for (int mt = 0; mt < 2; ++mt) {
            float v = fsum[mt];
            v += __shfl_xor(v, 16);
            v += __shfl_xor(v, 32);
            if (lane < 16) {
                const int m = r0 + mt * 16 + l15;
                out[(size_t)m * T + (t - 1)] = v + bfc1[0];
            }
        }
    }

    // z tile -> LDS transpose (per-wave 32x32, stride 36 floats = 144 B)
    char* zb = sm + w * 4608;
#pragma unroll
    for (int mt = 0; mt < 2; ++mt)
#pragma unroll
        for (int nt = 0; nt < 2; ++nt)
#pragma unroll
            for (int r = 0; r < 4; ++r)
                *(float*)(zb + (mt * 16 + quad * 4 + r) * 144 + (nt * 16 + l15) * 4)
                    = acc[mt][nt][r];
    __syncthreads();

    float* C = dir ? CB : CF;
#pragma unroll
    for (int p4 = 0; p4 < 4; ++p4) {
        const int idx = p4 * 64 + lane;
        const int ml = idx >> 3;      // 0..31
        const int ul = idx & 7;       // 0..7
        const f32x4 z = *(const f32x4*)(zb + ml * 144 + ul * 16);
        const f32x4 b4 = *(const f32x4*)(BR + nbase + c0 + ul * 4);
        const float zi = z[0] + b4[0], zf = z[1] + b4[1];
        const float zg = z[2] + b4[2], zo = z[3] + b4[3];
        const int u = colgrp * 16 + wc * 8 + ul;     // unit within direction
        const int m = r0 + ml;
        const size_t cidx = (size_t)m * 1024 + u;
        const float cold = C[cidx];
        const float c2 = sigm(zf) * cold + sigm(zi) * tanhf(zg);
        const float h2 = sigm(zo) * tanhf(c2);
        C[cidx] = c2;
        const size_t hidx = (size_t)m * 2048 + dir * 1024 + u;
        const u16 hh = f2bf(h2);
        NAh[hidx] = hh;
        NAl[hidx] = f2bf(h2 - bf2f(hh));
    }
}

// ---------------------------------------------------------------------------
// k_tail: out[:, T-1] from final A planes. 128 blocks (one per row).
// ---------------------------------------------------------------------------
__global__ __launch_bounds__(256) void k_tail(
    const u16* __restrict__ Ah, const u16* __restrict__ Al,
    const float* __restrict__ Wfc1, const float* __restrict__ bfc1,
    float* __restrict__ out, int T)
{
    __shared__ float red[256];
    const int m = blockIdx.x, tid = threadIdx.x;
    const size_t base = (size_t)m * 2048 + tid * 8;
    const short8 hv = *(const short8*)(Ah + base);
    const short8 lv = *(const short8*)(Al + base);
    float s = 0.0f;
#pragma unroll
    for (int e = 0; e < 8; ++e) {
        const float v = bf2f((u16)hv[e]) + bf2f((u16)lv[e]);
        s = fmaf(fmaxf(v, 0.0f), Wfc1[tid * 8 + e], s);
    }
    red[tid] = s;
    __syncthreads();
    for (int off = 128; off > 0; off >>= 1) {
        if (tid < off) red[tid] += red[tid + off];
        __syncthreads();
    }
    if (tid == 0) out[(size_t)m * T + T - 1] = red[0] + bfc1[0];
}

// ---------------------------------------------------------------------------
// k_fold: W'[col'][1024+j] = (Wih' @ WoT^T)[col'][j]  (+ Whh_b for bwd cols)
// ---------------------------------------------------------------------------
__global__ __launch_bounds__(256, 1) void k_fold(
    const u16* __restrict__ AH, const u16* __restrict__ AL,   // Wih' 8192x512
    const u16* __restrict__ BH, const u16* __restrict__ BL,   // WoT 1024x512
    const float* __restrict__ Whh_b,
    u16* __restrict__ WH, u16* __restrict__ WL)
{
    const int tid = threadIdx.x, bid = blockIdx.x;
    const int w = tid >> 6, lane = tid & 63, l15 = lane & 15, quad = lane >> 4;
    const int bm = bid >> 4, bn = bid & 15;
    const int ar0 = bm * 64 + (w & 1) * 32;
    const int br0 = bn * 64 + (w >> 1) * 32;
    f32x4 acc[2][2] = {};
    for (int k0 = 0; k0 < 512; k0 += 32) {
        short8 a_h[2], a_l[2], b_h[2], b_l[2];
#pragma unroll
        for (int mt = 0; mt < 2; ++mt) {
            const size_t o = (size_t)(ar0 + mt * 16 + l15) * 512 + k0 + quad * 8;
            a_h[mt] = *(const short8*)(AH + o);
            a_l[mt] = *(const short8*)(AL + o);
        }
#pragma unroll
        for (int nt = 0; nt < 2; ++nt) {
            const size_t o = (size_t)(br0 + nt * 16 + l15) * 512 + k0 + quad * 8;
            b_h[nt] = *(const short8*)(BH + o);
            b_l[nt] = *(const short8*)(BL + o);
        }
#pragma unroll
        for (int mt = 0; mt < 2; ++mt)
#pragma unroll
            for (int nt = 0; nt < 2; ++nt) {
                acc[mt][nt] = mfma16(a_h[mt], b_h[nt], acc[mt][nt]);
                acc[mt][nt] = mfma16(a_l[mt], b_h[nt], acc[mt][nt]);
                acc[mt][nt] = mfma16(a_h[mt], b_l[nt], acc[mt][nt]);
            }
    }
#pragma unroll
    for (int mt = 0; mt < 2; ++mt)
#pragma unroll
        for (int nt = 0; nt < 2; ++nt)
#pragma unroll
            for (int r = 0; r < 4; ++r) {
                const int row = ar0 + mt * 16 + quad * 4 + r;   // col'
                const int j = br0 + nt * 16 + l15;
                float v = acc[mt][nt][r];
                if (row >= 4096)
                    v += Whh_b[(size_t)((row & 3) * 1024 + ((row & 4095) >> 2)) * 1024 + j];
                const size_t d = (size_t)row * 2048 + 1024 + j;
                const u16 hh = f2bf(v);
                WH[d] = hh;
                WL[d] = f2bf(v - bf2f(hh));
            }
}

// ---------------------------------------------------------------------------
// k_prep: Wih' hi/lo, WoT hi/lo, BR0/BR1, A0 (x=dec), out=b_fc1, Whh_f -> W'.
// ---------------------------------------------------------------------------
__global__ __launch_bounds__(256) void k_prep(
    const float* __restrict__ dec,
    const float* __restrict__ Wih_f, const float* __restrict__ Whh_f,
    const float* __restrict__ b_f, const float* __restrict__ Wih_b,
    const float* __restrict__ b_b, const float* __restrict__ W_out,
    const float* __restrict__ b_out, const float* __restrict__ b_fc1,
    u16* __restrict__ WihH, u16* __restrict__ WihL,
    u16* __restrict__ WoTH, u16* __restrict__ WoTL,
    float* __restrict__ BR0, float* __restrict__ BR1,
    u16* __restrict__ A0h, u16* __restrict__ A0l,
    u16* __restrict__ WH, u16* __restrict__ WL,
    float* __restrict__ out, int out_size)
{
    const int t = blockIdx.x * 256 + threadIdx.x;
    if (t < 524288) {                       // Wih' (gate-interleaved cols, K=512)
        const int colp = t >> 6, kb = (t & 63) * 8;
        const int dir = colp >> 12, u = (colp & 4095) >> 2, g = colp & 3;
        const float* src = (dir ? Wih_b : Wih_f) + (size_t)(g * 1024 + u) * 512 + kb;
        const size_t d = (size_t)colp * 512 + kb;
#pragma unroll
        for (int j = 0; j < 8; ++j) {
            const float v = src[j];
            const u16 hh = f2bf(v);
            WihH[d + j] = hh; WihL[d + j] = f2bf(v - bf2f(hh));
        }
    } else if (t < 589824) {                // WoT[j][l] = W_out[l][j]
        const int i = t - 524288, jc = i >> 6, lb = (i & 63) * 8;
#pragma unroll
        for (int jj = 0; jj < 8; ++jj) {
            const float v = W_out[(size_t)(lb + jj) * 1024 + jc];
            const size_t d = (size_t)jc * 512 + lb + jj;
            const u16 hh = f2bf(v);
            WoTH[d] = hh; WoTL[d] = f2bf(v - bf2f(hh));
        }
    } else if (t < 598016) {                // biases
        const int colp = t - 589824;
        const int dir = colp >> 12, u = (colp & 4095) >> 2, g = colp & 3;
        const float* Wih = dir ? Wih_b : Wih_f;
        const float s = (dir ? b_b : b_f)[g * 1024 + u];
        BR0[colp] = s;
        float dot = 0.0f;
        for (int l = 0; l < 512; ++l)
            dot += Wih[(size_t)(g * 1024 + u) * 512 + l] * b_out[l];
        BR1[colp] = s + dot;
    } else if (t < 606208) {                // A0 = dec (cols [0,512), stride 2048)
        const int i = t - 598016, m = i >> 6, kb = (i & 63) * 8;
#pragma unroll
        for (int j = 0; j < 8; ++j) {
            const float v = dec[(size_t)m * 512 + kb + j];
            const size_t d = (size_t)m * 2048 + kb + j;
            const u16 hh = f2bf(v);
            A0h[d] = hh; A0l[d] = f2bf(v - bf2f(hh));
        }
    } else if (t < 614400) {                // out init = b_fc1 (safety net)
        const int base = (t - 606208) * 8;
        const float b0 = b_fc1[0];
#pragma unroll
        for (int j = 0; j < 8; ++j)
            if (base + j < out_size) out[base + j] = b0;
    } else {                                // Whh_f -> W' fwd cols, k in [0,1024)
        const int i = t - 614400, colp = i >> 7, kb = (i & 127) * 8;
        const int u = colp >> 2, g = colp & 3;
        const float* src = Whh_f + (size_t)(g * 1024 + u) * 1024 + kb;
        const size_t d = (size_t)colp * 2048 + kb;
#pragma unroll
        for (int j = 0; j < 8; ++j) {
            const float v = src[j];
            const u16 hh = f2bf(v);
            WH[d + j] = hh; WL[d + j] = f2bf(v - bf2f(hh));
        }
    }
}

// ---------------------------------------------------------------------------
// ws layout: see R3 (unchanged).
// ---------------------------------------------------------------------------
extern "C" void kernel_launch(void* const* d_in, const int* in_sizes, int n_in,
                              void* d_out, int out_size, void* d_ws, size_t ws_size,
                              hipStream_t stream) {
    const float* dec   = (const float*)d_in[0];
    const float* Wih_f = (const float*)d_in[2];
    const float* Whh_f = (const float*)d_in[3];
    const float* b_f   = (const float*)d_in[4];
    const float* Wih_b = (const float*)d_in[5];
    const float* Whh_b = (const float*)d_in[6];
    const float* b_b   = (const float*)d_in[7];
    const float* W_out = (const float*)d_in[8];
    const float* b_out = (const float*)d_in[9];
    const float* W_fc1 = (const float*)d_in[10];
    const float* b_fc1 = (const float*)d_in[11];
    float* out = (float*)d_out;

    char* ws = (char*)d_ws;
    u16* WH    = (u16*)(ws);
    u16* WL    = (u16*)(ws + 33554432);
    u16* WihH  = (u16*)(ws + 67108864);
    u16* WihL  = (u16*)(ws + 75497472);
    u16* WoTH  = (u16*)(ws + 83886080);
    u16* WoTL  = (u16*)(ws + 84934656);
    u16* A0h   = (u16*)(ws + 85983232);
    u16* A0l   = (u16*)(ws + 86507520);
    u16* A1h   = (u16*)(ws + 87031808);
    u16* A1l   = (u16*)(ws + 87556096);
    float* CF  = (float*)(ws + 88080384);
    float* CB  = (float*)(ws + 88604672);
    float* BR0 = (float*)(ws + 89128960);
    float* BR1 = (float*)(ws + 89161728);

    k_prep<<<4448, 256, 0, stream>>>(dec, Wih_f, Whh_f, b_f, Wih_b, b_b,
                                     W_out, b_out, b_fc1,
                                     WihH, WihL, WoTH, WoTL, BR0, BR1,
                                     A0h, A0l, WH, WL, out, out_size);
    k_fold<<<2048, 256, 0, stream>>>(WihH, WihL, WoTH, WoTL, Whh_b, WH, WL);
    hipMemsetAsync(CF, 0, 1048576, stream);   // CF + CB contiguous

    const int T = out_size / 128;
    u16* Abh[2] = {A0h, A1h};
    u16* Abl[2] = {A0l, A1l};
    for (int t = 0; t < T; ++t) {
        const int in = t & 1, nx = in ^ 1;
        if (t == 0) {
            k_step<<<256, 256, 0, stream>>>(A0h, A0l, A1h, A1l,
                                            WihH, WihL, 512, 0, 8, 0, 8,
                                            BR0, CF, CB, W_fc1, b_fc1, out, T, 0);
        } else {
            k_step<<<256, 256, 0, stream>>>(Abh[in], Abl[in], Abh[nx], Abl[nx],
                                            WH, WL, 2048, 0, 32, 1024, 16,
                                            BR1, CF, CB, W_fc1, b_fc1, out, T, t);
        }
    }
    k_tail<<<128, 256, 0, stream>>>(Abh[T & 1], Abl[T & 1], W_fc1, b_fc1, out, T);
}

// Round 6
// 21792.496 us; speedup vs baseline: 47.3649x; 1.2379x over previous
//
#include <hip/hip_runtime.h>
#include <math.h>

typedef unsigned short u16;
typedef __attribute__((ext_vector_type(8))) short short8;
typedef __attribute__((ext_vector_type(4))) float f32x4;

__device__ __forceinline__ float sigm(float x) { return 1.0f / (1.0f + expf(-x)); }

__device__ __forceinline__ u16 f2bf(float x) {
    union { float f; unsigned u; } v; v.f = x;
    unsigned r = v.u + 0x7fffu + ((v.u >> 16) & 1u);
    return (u16)(r >> 16);
}
__device__ __forceinline__ float bf2f(u16 h) {
    union { unsigned u; float f; } v; v.u = ((unsigned)h) << 16;
    return v.f;
}
__device__ __forceinline__ f32x4 mfma16(short8 a, short8 b, f32x4 c) {
    return __builtin_amdgcn_mfma_f32_16x16x32_bf16(a, b, c, 0, 0, 0);
}
__device__ __forceinline__ void gl_lds16(const void* g, void* l) {
    __builtin_amdgcn_global_load_lds(
        (const __attribute__((address_space(1))) unsigned int*)g,
        (__attribute__((address_space(3))) unsigned int*)l, 16, 0, 0);
}
__device__ __forceinline__ int swz(int c) { return (c ^ (c >> 2)) & 3; }

// ---------------------------------------------------------------------------
// k_step: ONE kernel per timestep.
//   z[m, col'] = A[m, koff..] @ W[col', koff..]^T + BR[col']   (3-product bf16)
//   col' = dir*4096 + u*4 + g. A = [hf | hb] (stride 2048) bf16 hi/lo.
//   Gates -> c (fp32 in place), h -> bf16 hi/lo into next-A planes.
//   fc1(t-1): fwd colgrp-0 blocks accumulate relu(hi+lo).Wfc1 from their
//   already-loaded A fragments; butterfly-reduce; plain store out[m,t-1].
// Grid 512 blocks (2 blocks/CU): dir = bid&1, rest: rowhalf, colgrp (128 x 32 cols).
// Block tile 64 rows x 32 cols; 4 waves of 16 rows x 32 cols (no dup A loads).
// K-chunk 64, LDS dbuf 2 x 8KB. Static register double-buffers (no spills).
// Two independent blocks per CU overlap each other's barrier/vmcnt drains.
// ---------------------------------------------------------------------------
#define STAGE_W(kk, buf)                                                      \
    do {                                                                      \
        _Pragma("unroll") for (int i_ = 0; i_ < 2; ++i_)                      \
            gl_lds16(Wsrc + soff[i_] + (kk),                                  \
                     sm + (buf) * 8192 + sldsoff[i_]);                        \
    } while (0)

#define LOAD_A(kk, AH_, AL_)                                                  \
    do {                                                                      \
        _Pragma("unroll") for (int ks_ = 0; ks_ < 2; ++ks_) {                 \
            AH_[ks_] = *(const short8*)(Ah + aoff + (kk) + ks_ * 32);         \
            AL_[ks_] = *(const short8*)(Al + aoff + (kk) + ks_ * 32);         \
        }                                                                     \
    } while (0)

#define COMPUTE(buf, AH_, AL_, cix)                                           \
    do {                                                                      \
        const char* bb_ = sm + (buf) * 8192;                                  \
        _Pragma("unroll") for (int ks_ = 0; ks_ < 2; ++ks_) {                 \
            short8 bh_[2], bl_[2];                                            \
            _Pragma("unroll") for (int nt_ = 0; nt_ < 2; ++nt_) {             \
                const int col_ = nt_ * 16 + l15;                              \
                const int off_ = ks_ * 2048 + col_ * 64 + ((quad ^ swz(col_)) * 16); \
                bh_[nt_] = *(const short8*)(bb_ + off_);                      \
                bl_[nt_] = *(const short8*)(bb_ + 4096 + off_);               \
            }                                                                 \
            _Pragma("unroll") for (int nt_ = 0; nt_ < 2; ++nt_) {             \
                acc[nt_] = mfma16(AH_[ks_], bh_[nt_], acc[nt_]);              \
                acc[nt_] = mfma16(AL_[ks_], bh_[nt_], acc[nt_]);              \
                acc[nt_] = mfma16(AH_[ks_], bl_[nt_], acc[nt_]);              \
            }                                                                 \
        }                                                                     \
        if (fc1w) {                                                           \
            const int kb_ = (cix) * 64 + quad * 8;                            \
            _Pragma("unroll") for (int ks_ = 0; ks_ < 2; ++ks_) {             \
                const float* wp_ = Wfc1 + kb_ + ks_ * 32;                     \
                const f32x4 w0_ = *(const f32x4*)(wp_);                       \
                const f32x4 w1_ = *(const f32x4*)(wp_ + 4);                   \
                const short8 hv_ = AH_[ks_];                                  \
                const short8 lv_ = AL_[ks_];                                  \
                _Pragma("unroll") for (int e_ = 0; e_ < 8; ++e_) {            \
                    const float v_ = bf2f((u16)hv_[e_]) + bf2f((u16)lv_[e_]); \
                    const float wv_ = (e_ < 4) ? w0_[e_] : w1_[e_ - 4];       \
                    fsum = fmaf(fmaxf(v_, 0.0f), wv_, fsum);                  \
                }                                                             \
            }                                                                 \
        }                                                                     \
    } while (0)

__global__ __launch_bounds__(256, 2) void k_step(
    const u16* __restrict__ Ah, const u16* __restrict__ Al,
    u16* __restrict__ NAh, u16* __restrict__ NAl,
    const u16* __restrict__ WH, const u16* __restrict__ WL, int wstride,
    int koff_f, int nch_f, int koff_b, int nch_b,
    const float* __restrict__ BR, float* __restrict__ CF, float* __restrict__ CB,
    const float* __restrict__ Wfc1, const float* __restrict__ bfc1,
    float* __restrict__ out, int T, int t)
{
    __shared__ __align__(16) char sm[16384];   // 2 x 8KB W bufs; epi reuses [0,9216)

    const int tid = threadIdx.x, bid = blockIdx.x;
    const int w = tid >> 6, lane = tid & 63, l15 = lane & 15, quad = lane >> 4;
    const int dir = bid & 1;
    const int rest = bid >> 1;
    const int rowhalf = rest >> 7, colgrp = rest & 127;
    const int nbase = dir * 4096 + colgrp * 32;
    const int koff = dir ? koff_b : koff_f;
    const int nch  = dir ? nch_b : nch_f;
    const int r0 = rowhalf * 64 + w * 16;    // this wave's 16 rows

    // fc1 duty: fwd colgrp-0 blocks (both rowhalves), all waves, t>0
    const bool fc1w = (t > 0) && (dir == 0) && (colgrp == 0);

    // --- staging role: plane sp (0 hi, 1 lo), k-half skh ---
    const int sp = w >> 1, skh = w & 1;
    const u16* Wsrc = sp ? WL : WH;
    size_t soff[2];
    int sldsoff[2];
#pragma unroll
    for (int i = 0; i < 2; ++i) {
        const int col = i * 16 + (lane >> 2);
        const int s = (lane & 3) ^ swz(col);
        soff[i] = (size_t)(nbase + col) * wstride + (size_t)(koff + skh * 32 + s * 8);
        sldsoff[i] = sp * 4096 + skh * 2048 + i * 1024;
    }

    // --- A fragment base offset (16 rows per wave, no duplication) ---
    const size_t aoff = (size_t)(r0 + l15) * 2048 + (size_t)(koff + quad * 8);

    f32x4 acc[2] = {};
    short8 ahA[2], alA[2], ahB[2], alB[2];   // static-indexed only
    float fsum = 0.0f;

    // prologue: stage chunk 0 -> LDS buf0, load A chunk 0 -> set A
    STAGE_W(0, 0);
    LOAD_A(0, ahA, alA);

    for (int c = 0; c < nch; c += 2) {
        __syncthreads();                     // buf0 staged
        {
            const int k1 = (c + 1) * 64;     // nch always even
            STAGE_W(k1, 1);
            LOAD_A(k1, ahB, alB);
        }
        COMPUTE(0, ahA, alA, c);
        __syncthreads();                     // buf1 staged; buf0 free
        if (c + 2 < nch) {
            const int k2 = (c + 2) * 64;
            STAGE_W(k2, 0);
            LOAD_A(k2, ahA, alA);
        }
        COMPUTE(1, ahB, alB, c + 1);
    }

    __syncthreads();    // all waves done with staging bufs before epi overwrite

    // fc1 reduce + store (no LDS, no atomics)
    if (fc1w) {
        float v = fsum;
        v += __shfl_xor(v, 16);
        v += __shfl_xor(v, 32);
        if (lane < 16) {
            const int m = r0 + l15;
            out[(size_t)m * T + (t - 1)] = v + bfc1[0];
        }
    }

    // z tile -> LDS transpose (per-wave 16x32, row stride 144 B)
    char* zb = sm + w * 2304;
#pragma unroll
    for (int nt = 0; nt < 2; ++nt)
#pragma unroll
        for (int r = 0; r < 4; ++r)
            *(float*)(zb + (quad * 4 + r) * 144 + (nt * 16 + l15) * 4) = acc[nt][r];
    __syncthreads();

    float* C = dir ? CB : CF;
#pragma unroll
    for (int p2 = 0; p2 < 2; ++p2) {
        const int idx = p2 * 64 + lane;      // 128 (m,u) pairs per wave
        const int ml = idx >> 3;             // 0..15
        const int ul = idx & 7;              // 0..7
        const f32x4 z = *(const f32x4*)(zb + ml * 144 + ul * 16);
        const f32x4 b4 = *(const f32x4*)(BR + nbase + ul * 4);
        const float zi = z[0] + b4[0], zf = z[1] + b4[1];
        const float zg = z[2] + b4[2], zo = z[3] + b4[3];
        const int u = colgrp * 8 + ul;       // unit within direction
        const int m = r0 + ml;
        const size_t cidx = (size_t)m * 1024 + u;
        const float cold = C[cidx];
        const float c2 = sigm(zf) * cold + sigm(zi) * tanhf(zg);
        const float h2 = sigm(zo) * tanhf(c2);
        C[cidx] = c2;
        const size_t hidx = (size_t)m * 2048 + dir * 1024 + u;
        const u16 hh = f2bf(h2);
        NAh[hidx] = hh;
        NAl[hidx] = f2bf(h2 - bf2f(hh));
    }
}

// ---------------------------------------------------------------------------
// k_tail: out[:, T-1] from final A planes. 128 blocks (one per row).
// ---------------------------------------------------------------------------
__global__ __launch_bounds__(256) void k_tail(
    const u16* __restrict__ Ah, const u16* __restrict__ Al,
    const float* __restrict__ Wfc1, const float* __restrict__ bfc1,
    float* __restrict__ out, int T)
{
    __shared__ float red[256];
    const int m = blockIdx.x, tid = threadIdx.x;
    const size_t base = (size_t)m * 2048 + tid * 8;
    const short8 hv = *(const short8*)(Ah + base);
    const short8 lv = *(const short8*)(Al + base);
    float s = 0.0f;
#pragma unroll
    for (int e = 0; e < 8; ++e) {
        const float v = bf2f((u16)hv[e]) + bf2f((u16)lv[e]);
        s = fmaf(fmaxf(v, 0.0f), Wfc1[tid * 8 + e], s);
    }
    red[tid] = s;
    __syncthreads();
    for (int off = 128; off > 0; off >>= 1) {
        if (tid < off) red[tid] += red[tid + off];
        __syncthreads();
    }
    if (tid == 0) out[(size_t)m * T + T - 1] = red[0] + bfc1[0];
}

// ---------------------------------------------------------------------------
// k_fold: W'[col'][1024+j] = (Wih' @ WoT^T)[col'][j]  (+ Whh_b for bwd cols)
// ---------------------------------------------------------------------------
__global__ __launch_bounds__(256, 1) void k_fold(
    const u16* __restrict__ AH, const u16* __restrict__ AL,   // Wih' 8192x512
    const u16* __restrict__ BH, const u16* __restrict__ BL,   // WoT 1024x512
    const float* __restrict__ Whh_b,
    u16* __restrict__ WH, u16* __restrict__ WL)
{
    const int tid = threadIdx.x, bid = blockIdx.x;
    const int w = tid >> 6, lane = tid & 63, l15 = lane & 15, quad = lane >> 4;
    const int bm = bid >> 4, bn = bid & 15;
    const int ar0 = bm * 64 + (w & 1) * 32;
    const int br0 = bn * 64 + (w >> 1) * 32;
    f32x4 acc[2][2] = {};
    for (int k0 = 0; k0 < 512; k0 += 32) {
        short8 a_h[2], a_l[2], b_h[2], b_l[2];
#pragma unroll
        for (int mt = 0; mt < 2; ++mt) {
            const size_t o = (size_t)(ar0 + mt * 16 + l15) * 512 + k0 + quad * 8;
            a_h[mt] = *(const short8*)(AH + o);
            a_l[mt] = *(const short8*)(AL + o);
        }
#pragma unroll
        for (int nt = 0; nt < 2; ++nt) {
            const size_t o = (size_t)(br0 + nt * 16 + l15) * 512 + k0 + quad * 8;
            b_h[nt] = *(const short8*)(BH + o);
            b_l[nt] = *(const short8*)(BL + o);
        }
#pragma unroll
        for (int mt = 0; mt < 2; ++mt)
#pragma unroll
            for (int nt = 0; nt < 2; ++nt) {
                acc[mt][nt] = mfma16(a_h[mt], b_h[nt], acc[mt][nt]);
                acc[mt][nt] = mfma16(a_l[mt], b_h[nt], acc[mt][nt]);
                acc[mt][nt] = mfma16(a_h[mt], b_l[nt], acc[mt][nt]);
            }
    }
#pragma unroll
    for (int mt = 0; mt < 2; ++mt)
#pragma unroll
        for (int nt = 0; nt < 2; ++nt)
#pragma unroll
            for (int r = 0; r < 4; ++r) {
                const int row = ar0 + mt * 16 + quad * 4 + r;   // col'
                const int j = br0 + nt * 16 + l15;
                float v = acc[mt][nt][r];
                if (row >= 4096)
                    v += Whh_b[(size_t)((row & 3) * 1024 + ((row & 4095) >> 2)) * 1024 + j];
                const size_t d = (size_t)row * 2048 + 1024 + j;
                const u16 hh = f2bf(v);
                WH[d] = hh;
                WL[d] = f2bf(v - bf2f(hh));
            }
}

// ---------------------------------------------------------------------------
// k_prep: Wih' hi/lo, WoT hi/lo, BR0/BR1, A0 (x=dec), out=b_fc1, Whh_f -> W'.
// ---------------------------------------------------------------------------
__global__ __launch_bounds__(256) void k_prep(
    const float* __restrict__ dec,
    const float* __restrict__ Wih_f, const float* __restrict__ Whh_f,
    const float* __restrict__ b_f, const float* __restrict__ Wih_b,
    const float* __restrict__ b_b, const float* __restrict__ W_out,
    const float* __restrict__ b_out, const float* __restrict__ b_fc1,
    u16* __restrict__ WihH, u16* __restrict__ WihL,
    u16* __restrict__ WoTH, u16* __restrict__ WoTL,
    float* __restrict__ BR0, float* __restrict__ BR1,
    u16* __restrict__ A0h, u16* __restrict__ A0l,
    u16* __restrict__ WH, u16* __restrict__ WL,
    float* __restrict__ out, int out_size)
{
    const int t = blockIdx.x * 256 + threadIdx.x;
    if (t < 524288) {                       // Wih' (gate-interleaved cols, K=512)
        const int colp = t >> 6, kb = (t & 63) * 8;
        const int dir = colp >> 12, u = (colp & 4095) >> 2, g = colp & 3;
        const float* src = (dir ? Wih_b : Wih_f) + (size_t)(g * 1024 + u) * 512 + kb;
        const size_t d = (size_t)colp * 512 + kb;
#pragma unroll
        for (int j = 0; j < 8; ++j) {
            const float v = src[j];
            const u16 hh = f2bf(v);
            WihH[d + j] = hh; WihL[d + j] = f2bf(v - bf2f(hh));
        }
    } else if (t < 589824) {                // WoT[j][l] = W_out[l][j]
        const int i = t - 524288, jc = i >> 6, lb = (i & 63) * 8;
#pragma unroll
        for (int jj = 0; jj < 8; ++jj) {
            const float v = W_out[(size_t)(lb + jj) * 1024 + jc];
            const size_t d = (size_t)jc * 512 + lb + jj;
            const u16 hh = f2bf(v);
            WoTH[d] = hh; WoTL[d] = f2bf(v - bf2f(hh));
        }
    } else if (t < 598016) {                // biases
        const int colp = t - 589824;
        const int dir = colp >> 12, u = (colp & 4095) >> 2, g = colp & 3;
        const float* Wih = dir ? Wih_b : Wih_f;
        const float s = (dir ? b_b : b_f)[g * 1024 + u];
        BR0[colp] = s;
        float dot = 0.0f;
        for (int l = 0; l < 512; ++l)
            dot += Wih[(size_t)(g * 1024 + u) * 512 + l] * b_out[l];
        BR1[colp] = s + dot;
    } else if (t < 606208) {                // A0 = dec (cols [0,512), stride 2048)
        const int i = t - 598016, m = i >> 6, kb = (i & 63) * 8;
#pragma unroll
        for (int j = 0; j < 8; ++j) {
            const float v = dec[(size_t)m * 512 + kb + j];
            const size_t d = (size_t)m * 2048 + kb + j;
            const u16 hh = f2bf(v);
            A0h[d] = hh; A0l[d] = f2bf(v - bf2f(hh));
        }
    } else if (t < 614400) {                // out init = b_fc1 (safety net)
        const int base = (t - 606208) * 8;
        const float b0 = b_fc1[0];
#pragma unroll
        for (int j = 0; j < 8; ++j)
            if (base + j < out_size) out[base + j] = b0;
    } else {                                // Whh_f -> W' fwd cols, k in [0,1024)
        const int i = t - 614400, colp = i >> 7, kb = (i & 127) * 8;
        const int u = colp >> 2, g = colp & 3;
        const float* src = Whh_f + (size_t)(g * 1024 + u) * 1024 + kb;
        const size_t d = (size_t)colp * 2048 + kb;
#pragma unroll
        for (int j = 0; j < 8; ++j) {
            const float v = src[j];
            const u16 hh = f2bf(v);
            WH[d + j] = hh; WL[d + j] = f2bf(v - bf2f(hh));
        }
    }
}

// ---------------------------------------------------------------------------
// ws layout: see R3 (unchanged).
// ---------------------------------------------------------------------------
extern "C" void kernel_launch(void* const* d_in, const int* in_sizes, int n_in,
                              void* d_out, int out_size, void* d_ws, size_t ws_size,
                              hipStream_t stream) {
    const float* dec   = (const float*)d_in[0];
    const float* Wih_f = (const float*)d_in[2];
    const float* Whh_f = (const float*)d_in[3];
    const float* b_f   = (const float*)d_in[4];
    const float* Wih_b = (const float*)d_in[5];
    const float* Whh_b = (const float*)d_in[6];
    const float* b_b   = (const float*)d_in[7];
    const float* W_out = (const float*)d_in[8];
    const float* b_out = (const float*)d_in[9];
    const float* W_fc1 = (const float*)d_in[10];
    const float* b_fc1 = (const float*)d_in[11];
    float* out = (float*)d_out;

    char* ws = (char*)d_ws;
    u16* WH    = (u16*)(ws);
    u16* WL    = (u16*)(ws + 33554432);
    u16* WihH  = (u16*)(ws + 67108864);
    u16* WihL  = (u16*)(ws + 75497472);
    u16* WoTH  = (u16*)(ws + 83886080);
    u16* WoTL  = (u16*)(ws + 84934656);
    u16* A0h   = (u16*)(ws + 85983232);
    u16* A0l   = (u16*)(ws + 86507520);
    u16* A1h   = (u16*)(ws + 87031808);
    u16* A1l   = (u16*)(ws + 87556096);
    float* CF  = (float*)(ws + 88080384);
    float* CB  = (float*)(ws + 88604672);
    float* BR0 = (float*)(ws + 89128960);
    float* BR1 = (float*)(ws + 89161728);

    k_prep<<<4448, 256, 0, stream>>>(dec, Wih_f, Whh_f, b_f, Wih_b, b_b,
                                     W_out, b_out, b_fc1,
                                     WihH, WihL, WoTH, WoTL, BR0, BR1,
                                     A0h, A0l, WH, WL, out, out_size);
    k_fold<<<2048, 256, 0, stream>>>(WihH, WihL, WoTH, WoTL, Whh_b, WH, WL);
    hipMemsetAsync(CF, 0, 1048576, stream);   // CF + CB contiguous

    const int T = out_size / 128;
    u16* Abh[2] = {A0h, A1h};
    u16* Abl[2] = {A0l, A1l};
    for (int t = 0; t < T; ++t) {
        const int in = t & 1, nx = in ^ 1;
        if (t == 0) {
            k_step<<<512, 256, 0, stream>>>(A0h, A0l, A1h, A1l,
                                            WihH, WihL, 512, 0, 8, 0, 8,
                                            BR0, CF, CB, W_fc1, b_fc1, out, T, 0);
        } else {
            k_step<<<512, 256, 0, stream>>>(Abh[in], Abl[in], Abh[nx], Abl[nx],
                                            WH, WL, 2048, 0, 32, 1024, 16,
                                            BR1, CF, CB, W_fc1, b_fc1, out, T, t);
        }
    }
    k_tail<<<128, 256, 0, stream>>>(Abh[T & 1], Abl[T & 1], W_fc1, b_fc1, out, T);
}